// Round 4
// baseline (432.502 us; speedup 1.0000x reference)
//
#include <hip/hip_runtime.h>
#include <math.h>

#define LSEQ 2048
#define KNB 64
#define BATCH 8
#define MRBF 7
#define TOTPAIR (BATCH*LSEQ*KNB)
#define NGROUP (TOTPAIR/32)      // 32768 groups of 32 pairs (half a row each)
#define BSCALE (255.0f/144.0f)

typedef __attribute__((ext_vector_type(8))) short short8;
typedef __attribute__((ext_vector_type(4))) float floatx4;
typedef __attribute__((ext_vector_type(4))) int int4v;

// RNE float->bf16 (weight setup, cold path)
__device__ __forceinline__ unsigned short f2bf(float f) {
    unsigned u = __float_as_uint(f);
    u += 0x7fffu + ((u >> 16) & 1u);
    return (unsigned short)(u >> 16);
}
// packed round-half-up bf16x2 in 3 ops via v_perm (a -> low half, b -> high half)
__device__ __forceinline__ unsigned pkbf(float a, float b) {
    return __builtin_amdgcn_perm(__float_as_uint(b) + 0x8000u,
                                 __float_as_uint(a) + 0x8000u, 0x07060302u);
}

// ---------------------------------------------------------------------------
// Kernel 1: top-K=64 per row. 4 rows/block; R[b] staged once in LDS; 255-bin
// histogram over d2<144 only (r>=12 contributes exactly 0 via smoothstep, so
// ordering there is irrelevant); boundary bin resolved by exact rank.
// ---------------------------------------------------------------------------
__global__ __launch_bounds__(256) void topk_kernel(
    const float* __restrict__ R, int* __restrict__ nbr)
{
    __shared__ __align__(16) float Rl[LSEQ*3];
    __shared__ unsigned hist[4*256];
    __shared__ float cand_d2[4][128];
    __shared__ int   cand_j[4][128];
    __shared__ int s_B[4], s_need[4];
    __shared__ int outPos[4], candCnt[4], fillCnt[4];

    const int tid = threadIdx.x;
    const int lane = tid & 63;
    const int wv = tid >> 6;
    const int b  = blockIdx.x >> 9;
    const int i0 = (blockIdx.x & 511) << 2;
    const float* Rb = R + b*LSEQ*3;

    for (int u = tid; u < LSEQ*3/4; u += 256)
        *(float4*)&Rl[u*4] = *(const float4*)&Rb[u*4];
    #pragma unroll
    for (int u = 0; u < 4; u++) hist[tid + 256*u] = 0u;
    if (tid < 4) { outPos[tid] = 0; candCnt[tid] = 0; fillCnt[tid] = 0; }
    __syncthreads();

    float xi[4], yi[4], zi[4];
    #pragma unroll
    for (int c = 0; c < 4; c++) {
        xi[c] = Rl[(i0+c)*3+0]; yi[c] = Rl[(i0+c)*3+1]; zi[c] = Rl[(i0+c)*3+2];
    }

    // pass 1: histogram (in-cutoff, non-bonded only)
    #pragma unroll
    for (int u = 0; u < 8; u++) {
        int j = tid + (u << 8);
        float px = Rl[3*j], py = Rl[3*j+1], pz = Rl[3*j+2];
        #pragma unroll
        for (int c = 0; c < 4; c++) {
            float dx = xi[c]-px, dy = yi[c]-py, dz = zi[c]-pz;
            float d2 = dx*dx + dy*dy + dz*dz;
            int dd = j - (i0+c); dd = dd < 0 ? -dd : dd;
            if (dd > 3 && d2 < 144.0f)
                atomicAdd(&hist[c*256 + (int)(d2*BSCALE)], 1u);
        }
    }
    __syncthreads();

    // scan: wave wv owns row wv; lane covers bins 4*lane..4*lane+3
    {
        unsigned h4[4]; unsigned s = 0;
        #pragma unroll
        for (int v = 0; v < 4; v++) { h4[v] = hist[wv*256 + lane*4 + v]; s += h4[v]; }
        unsigned inc = s;
        #pragma unroll
        for (int off = 1; off < 64; off <<= 1) {
            unsigned n = __shfl_up(inc, off, 64);
            if (lane >= off) inc += n;
        }
        unsigned tot = __shfl(inc, 63, 64);
        unsigned excl = inc - s;
        if (tot < 64u) {
            if (lane == 0) { s_B[wv] = 255; s_need[wv] = 64 - (int)tot; }
        } else if (excl < 64u && 64u <= inc) {
            unsigned cc = excl;
            #pragma unroll
            for (int v = 0; v < 4; v++) {
                if (cc < 64u && 64u <= cc + h4[v]) { s_B[wv] = lane*4+v; s_need[wv] = 64 - (int)cc; }
                cc += h4[v];
            }
        }
    }
    __syncthreads();

    // pass 2: compact winners / boundary candidates / far-fill
    #pragma unroll
    for (int u = 0; u < 8; u++) {
        int j = tid + (u << 8);
        float px = Rl[3*j], py = Rl[3*j+1], pz = Rl[3*j+2];
        #pragma unroll
        for (int c = 0; c < 4; c++) {
            float dx = xi[c]-px, dy = yi[c]-py, dz = zi[c]-pz;
            float d2 = dx*dx + dy*dy + dz*dz;
            int dd = j - (i0+c); dd = dd < 0 ? -dd : dd;
            if (dd <= 3) continue;
            int B = s_B[c];
            int obase = (b*LSEQ + i0 + c)*KNB;
            if (d2 < 144.0f) {
                int key = (int)(d2*BSCALE);
                if (key < B) {
                    int pos = atomicAdd(&outPos[c], 1);
                    nbr[obase + pos] = j;
                } else if (key == B) {
                    int cc = atomicAdd(&candCnt[c], 1);
                    if (cc < 128) { cand_d2[c][cc] = d2; cand_j[c][cc] = j; }
                }
            } else if (B == 255) {
                // fewer than 64 inside cutoff: fill with r>=12 pairs (exactly 0)
                int t = atomicAdd(&fillCnt[c], 1);
                if (t < s_need[c]) {
                    int pos = atomicAdd(&outPos[c], 1);
                    nbr[obase + pos] = j;
                }
            }
        }
    }
    __syncthreads();

    // boundary bin: exact rank (wave wv owns row wv)
    {
        int B = s_B[wv];
        if (B != 255) {
            int c = candCnt[wv]; if (c > 128) c = 128;
            int need = s_need[wv];
            int obase = (b*LSEQ + i0 + wv)*KNB;
            for (int ci = lane; ci < c; ci += 64) {
                float dv = cand_d2[wv][ci]; int jv = cand_j[wv][ci];
                int rank = 0;
                for (int x = 0; x < c; x++) {
                    float dx2 = cand_d2[wv][x]; int jx = cand_j[wv][x];
                    rank += (dx2 < dv) || (dx2 == dv && jx < jv);
                }
                if (rank < need) {
                    int pos = atomicAdd(&outPos[wv], 1);
                    nbr[obase + pos] = jv;
                }
            }
        }
    }
}

// ---------------------------------------------------------------------------
// Kernel 2: register-resident MFMA MLP. Each wave owns ALL weight fragments
// and processes 32 pairs (half a row) per iteration, LDS-free & barrier-free.
// Inter-GEMM transpose = cross-quad shuffles (D cols and B cols are both the
// pair index l15). Layouts (verified end-to-end by round-2's absmax=0 pass):
//   A[m][k]: m=lane&15, k=quad*8+j | B[k][n]: n=lane&15, k=quad*8+j
//   D[r][c]: c=lane&15, r=quad*4+reg
// ---------------------------------------------------------------------------
__device__ __forceinline__ short8 gather_frag(unsigned pA0, unsigned pA1,
                                              unsigned pB0, unsigned pB1,
                                              int src0, bool hi)
{
    // dest lane (q,l15) needs neurons kt*32+q*8+0..7 of pair l15:
    //   mtl = 2kt+(q>>1)  -> select pA(=2kt) vs pB(=2kt+1)
    //   src lanes l15+16*(2(q&1)) and +16, both dwords each
    int a0 = __shfl((int)pA0, src0,      64);
    int a1 = __shfl((int)pA1, src0,      64);
    int a2 = __shfl((int)pA0, src0 + 16, 64);
    int a3 = __shfl((int)pA1, src0 + 16, 64);
    int c0 = __shfl((int)pB0, src0,      64);
    int c1 = __shfl((int)pB1, src0,      64);
    int c2 = __shfl((int)pB0, src0 + 16, 64);
    int c3 = __shfl((int)pB1, src0 + 16, 64);
    int4v r;
    r[0] = hi ? c0 : a0; r[1] = hi ? c1 : a1;
    r[2] = hi ? c2 : a2; r[3] = hi ? c3 : a3;
    return __builtin_bit_cast(short8, r);
}

__device__ __forceinline__ void ldgrp(int g, int q, int l15,
    const int* __restrict__ nbr, const int* __restrict__ seq,
    const float* __restrict__ emb, const float* __restrict__ R,
    float v[2][8], float rc[2][6])
{
    #pragma unroll
    for (int t = 0; t < 2; t++) {
        int p = g*32 + t*16 + l15;
        int bi = p >> 6;
        int bb = p >> 17;
        int j  = nbr[p];
        int rowj = (bb << 11) + j;
        int srow = (q < 2) ? bi : rowj;
        int s = seq[srow];
        const float* ep = emb + s*16 + (q & 1)*8;
        float4 e0 = *(const float4*)ep;
        float4 e1 = *(const float4*)(ep + 4);
        v[t][0]=e0.x; v[t][1]=e0.y; v[t][2]=e0.z; v[t][3]=e0.w;
        v[t][4]=e1.x; v[t][5]=e1.y; v[t][6]=e1.z; v[t][7]=e1.w;
        rc[t][0]=R[bi*3+0];   rc[t][1]=R[bi*3+1];   rc[t][2]=R[bi*3+2];
        rc[t][3]=R[rowj*3+0]; rc[t][4]=R[rowj*3+1]; rc[t][5]=R[rowj*3+2];
    }
}

__global__ __launch_bounds__(256, 1) void mlp_kernel(
    const float* __restrict__ R, const int* __restrict__ seq,
    const float* __restrict__ emb,
    const float* __restrict__ W1, const float* __restrict__ b1,
    const float* __restrict__ W2, const float* __restrict__ b2,
    const float* __restrict__ W3, const float* __restrict__ b3,
    const float* __restrict__ centers, const float* __restrict__ widths,
    const int* __restrict__ nbr, float* __restrict__ out)
{
    const int tid = threadIdx.x;
    const int lane = tid & 63;
    const int wv = tid >> 6;
    const int l15 = lane & 15;
    const int q = lane >> 4;

    // ---- all weights as persistent A-operand fragments ----
    short8 w1f[8][2], w2f[8][4], w3f[4];
    float b1v[8][4], b2v[8][4];
    #pragma unroll
    for (int mtl = 0; mtl < 8; mtl++) {
        int m = mtl*16 + l15;
        #pragma unroll
        for (int d = 0; d < 4; d++) {
            b1v[mtl][d] = b1[mtl*16 + q*4 + d];
            b2v[mtl][d] = b2[mtl*16 + q*4 + d];
        }
        #pragma unroll
        for (int kt = 0; kt < 2; kt++)
            #pragma unroll
            for (int jj = 0; jj < 8; jj++) {
                int k = kt*32 + q*8 + jj;
                w1f[mtl][kt][jj] = (short)((k < 48) ? f2bf(W1[k*128 + m]) : 0);
            }
        #pragma unroll
        for (int kt = 0; kt < 4; kt++)
            #pragma unroll
            for (int jj = 0; jj < 8; jj++) {
                int k = kt*32 + q*8 + jj;
                w2f[mtl][kt][jj] = (short)f2bf(W2[k*128 + m]);
            }
    }
    #pragma unroll
    for (int kt = 0; kt < 4; kt++)
        #pragma unroll
        for (int jj = 0; jj < 8; jj++) {
            int k = kt*32 + q*8 + jj;
            w3f[kt][jj] = (short)((l15 < MRBF) ? f2bf(W3[k*MRBF + l15]) : 0);
        }
    float b3C[4], cen[4], i2w[4];
    #pragma unroll
    for (int d = 0; d < 4; d++) {
        int rb = q*4 + d;
        bool ok = rb < MRBF;
        b3C[d] = ok ? b3[rb] : 0.f;
        cen[d] = ok ? centers[rb] : 0.f;
        float wd = ok ? widths[rb] : 1.f;
        i2w[d] = 0.5f / (wd*wd);
    }

    const int src0 = l15 + 32*(q & 1);
    const bool hi = (q >> 1) != 0;
    const int GS = gridDim.x * 4;
    const int gw = blockIdx.x*4 + wv;

    float vcur[2][8], rcur[2][6];
    float esum = 0.f;
    int bcur = -1;
    if (gw < NGROUP) { ldgrp(gw, q, l15, nbr, seq, emb, R, vcur, rcur); bcur = gw >> 12; }

    for (int g = gw; g < NGROUP; g += GS) {
        // software-pipelined prefetch of next group's nbr->seq->emb chain
        int gn = g + GS;
        float vnx[2][8], rnx[2][6];
        bool hn = gn < NGROUP;
        if (hn) ldgrp(gn, q, l15, nbr, seq, emb, R, vnx, rnx);

        int bb = g >> 12;
        if (bb != bcur) {
            float s_ = esum;
            #pragma unroll
            for (int off = 1; off < 64; off <<= 1) s_ += __shfl_xor(s_, off, 64);
            if (lane == 0) atomicAdd(&out[bcur], s_*0.25f);
            esum = 0.f; bcur = bb;
        }

        #pragma unroll
        for (int t = 0; t < 2; t++) {
            // ---- X fragments in-register ----
            int4v xi0;
            xi0[0] = (int)pkbf(vcur[t][0], vcur[t][1]);
            xi0[1] = (int)pkbf(vcur[t][2], vcur[t][3]);
            xi0[2] = (int)pkbf(vcur[t][4], vcur[t][5]);
            xi0[3] = (int)pkbf(vcur[t][6], vcur[t][7]);
            short8 x0 = __builtin_bit_cast(short8, xi0);
            float pr[8];
            #pragma unroll
            for (int f = 0; f < 8; f++)
                pr[f] = vcur[t][f] * __shfl_xor(vcur[t][f], 32, 64);
            bool lo2 = q < 2;
            int4v xi1;
            xi1[0] = lo2 ? (int)pkbf(pr[0], pr[1]) : 0;
            xi1[1] = lo2 ? (int)pkbf(pr[2], pr[3]) : 0;
            xi1[2] = lo2 ? (int)pkbf(pr[4], pr[5]) : 0;
            xi1[3] = lo2 ? (int)pkbf(pr[6], pr[7]) : 0;
            short8 x1 = __builtin_bit_cast(short8, xi1);

            // ---- GEMM1 (bias as MFMA C-operand) ----
            unsigned pk1[8][2];
            #pragma unroll
            for (int mtl = 0; mtl < 8; mtl++) {
                floatx4 acc = {b1v[mtl][0], b1v[mtl][1], b1v[mtl][2], b1v[mtl][3]};
                acc = __builtin_amdgcn_mfma_f32_16x16x32_bf16(w1f[mtl][0], x0, acc, 0, 0, 0);
                acc = __builtin_amdgcn_mfma_f32_16x16x32_bf16(w1f[mtl][1], x1, acc, 0, 0, 0);
                pk1[mtl][0] = pkbf(fmaxf(acc[0],0.f), fmaxf(acc[1],0.f));
                pk1[mtl][1] = pkbf(fmaxf(acc[2],0.f), fmaxf(acc[3],0.f));
            }
            // ---- transpose via shuffles -> H1 B-fragments ----
            short8 hf[4];
            #pragma unroll
            for (int kt = 0; kt < 4; kt++)
                hf[kt] = gather_frag(pk1[2*kt][0], pk1[2*kt][1],
                                     pk1[2*kt+1][0], pk1[2*kt+1][1], src0, hi);
            // ---- GEMM2 ----
            unsigned pk2[8][2];
            #pragma unroll
            for (int mtl = 0; mtl < 8; mtl++) {
                floatx4 acc = {b2v[mtl][0], b2v[mtl][1], b2v[mtl][2], b2v[mtl][3]};
                acc = __builtin_amdgcn_mfma_f32_16x16x32_bf16(w2f[mtl][0], hf[0], acc, 0, 0, 0);
                acc = __builtin_amdgcn_mfma_f32_16x16x32_bf16(w2f[mtl][1], hf[1], acc, 0, 0, 0);
                acc = __builtin_amdgcn_mfma_f32_16x16x32_bf16(w2f[mtl][2], hf[2], acc, 0, 0, 0);
                acc = __builtin_amdgcn_mfma_f32_16x16x32_bf16(w2f[mtl][3], hf[3], acc, 0, 0, 0);
                pk2[mtl][0] = pkbf(fmaxf(acc[0],0.f), fmaxf(acc[1],0.f));
                pk2[mtl][1] = pkbf(fmaxf(acc[2],0.f), fmaxf(acc[3],0.f));
            }
            // ---- transpose -> H2 B-fragments ----
            short8 h2[4];
            #pragma unroll
            for (int kt = 0; kt < 4; kt++)
                h2[kt] = gather_frag(pk2[2*kt][0], pk2[2*kt][1],
                                     pk2[2*kt+1][0], pk2[2*kt+1][1], src0, hi);
            // ---- GEMM3 + epilogue ----
            floatx4 a3 = {b3C[0], b3C[1], b3C[2], b3C[3]};
            #pragma unroll
            for (int kt = 0; kt < 4; kt++)
                a3 = __builtin_amdgcn_mfma_f32_16x16x32_bf16(w3f[kt], h2[kt], a3, 0, 0, 0);

            float dx = rcur[t][0]-rcur[t][3];
            float dy = rcur[t][1]-rcur[t][4];
            float dz = rcur[t][2]-rcur[t][5];
            float r = sqrtf(dx*dx + dy*dy + dz*dz + 1e-12f);
            float att = 0.f;
            #pragma unroll
            for (int d = 0; d < 4; d++) {
                if (q*4 + d < MRBF) {
                    float x = a3[d];
                    float sp = fmaxf(x, 0.f) + __logf(1.f + __expf(-fabsf(x)));
                    float df = r - cen[d];
                    att += sp * __expf(-df*df*i2w[d]);
                }
            }
            att += __shfl_xor(att, 16, 64);
            att += __shfl_xor(att, 32, 64);
            float tt = fminf(fmaxf((r - 10.f)*0.5f, 0.f), 1.f);
            float sw = 1.f - tt*tt*(3.f - 2.f*tt);
            esum -= att * sw;       // 4x quad-replicated; scaled by 0.25 at flush
        }

        if (hn) {
            #pragma unroll
            for (int t = 0; t < 2; t++) {
                #pragma unroll
                for (int f = 0; f < 8; f++) vcur[t][f] = vnx[t][f];
                #pragma unroll
                for (int f = 0; f < 6; f++) rcur[t][f] = rnx[t][f];
            }
        }
    }
    if (bcur >= 0) {
        float s_ = esum;
        #pragma unroll
        for (int off = 1; off < 64; off <<= 1) s_ += __shfl_xor(s_, off, 64);
        if (lane == 0) atomicAdd(&out[bcur], s_*0.25f);
    }
}

// ---------------------------------------------------------------------------
extern "C" void kernel_launch(void* const* d_in, const int* in_sizes, int n_in,
                              void* d_out, int out_size, void* d_ws, size_t ws_size,
                              hipStream_t stream) {
    const float* R       = (const float*)d_in[0];
    const int*   seq     = (const int*)  d_in[1];
    const float* emb     = (const float*)d_in[2];
    const float* W1      = (const float*)d_in[3];
    const float* b1      = (const float*)d_in[4];
    const float* W2      = (const float*)d_in[5];
    const float* b2      = (const float*)d_in[6];
    const float* W3      = (const float*)d_in[7];
    const float* b3      = (const float*)d_in[8];
    const float* centers = (const float*)d_in[9];
    const float* widths  = (const float*)d_in[10];
    float* out = (float*)d_out;
    int*   nbr = (int*)d_ws;   // TOTPAIR ints = 4 MiB

    hipMemsetAsync(d_out, 0, out_size * sizeof(float), stream);

    topk_kernel<<<BATCH*(LSEQ/4), 256, 0, stream>>>(R, nbr);
    mlp_kernel<<<512, 256, 0, stream>>>(R, seq, emb, W1, b1, W2, b2, W3, b3,
                                        centers, widths, nbr, out);
}

// Round 5
// 311.442 us; speedup vs baseline: 1.3887x; 1.3887x over previous
//
#include <hip/hip_runtime.h>
#include <math.h>

#define LSEQ 2048
#define KNB 64
#define BATCH 8
#define MRBF 7
#define NPAIRS (BATCH*LSEQ*KNB)
#define NTILES (NPAIRS/128)
#define XST 72    // X LDS stride (bf16): 64 data + 8 pad -> 144B rows, 16B-aligned frags
#define HST 136   // H LDS stride: 128 + 8 pad -> 272B rows, 16B-aligned frags
#define TROWS 8
#define BSCALE (255.0f/144.0f)

typedef __attribute__((ext_vector_type(8))) short short8;
typedef __attribute__((ext_vector_type(4))) float floatx4;

// RNE float->bf16 (cold path: weight setup)
__device__ __forceinline__ unsigned short f2bf(float f) {
    unsigned u = __float_as_uint(f);
    u += 0x7fffu + ((u >> 16) & 1u);
    return (unsigned short)(u >> 16);
}
// packed round-half-up bf16x2, 3 ops via v_perm (r4-proven on HW)
__device__ __forceinline__ unsigned pkbf(float a, float b) {
    return __builtin_amdgcn_perm(__float_as_uint(b) + 0x8000u,
                                 __float_as_uint(a) + 0x8000u, 0x07060302u);
}

// ---------------------------------------------------------------------------
// Kernel 1: exact top-K=64 per row; 8 rows/block, R[b] staged once in LDS.
// 255-bin histogram over d2<144 only (r>=12 contributes exactly 0 via the
// smoothstep switch, so selection beyond cutoff is irrelevant -> fill set).
// Boundary bin resolved by exact (d2, j) rank.
// ---------------------------------------------------------------------------
__global__ __launch_bounds__(256) void topk_kernel(
    const float* __restrict__ R, int* __restrict__ nbr)
{
    __shared__ __align__(16) float Rl[LSEQ*3];
    __shared__ unsigned hist[TROWS*256];
    __shared__ float cand_d2[TROWS][128];
    __shared__ int   cand_j[TROWS][128];
    __shared__ int s_B[TROWS], s_need[TROWS];
    __shared__ int outPos[TROWS], candCnt[TROWS], fillCnt[TROWS];

    const int tid = threadIdx.x;
    const int lane = tid & 63;
    const int wv = tid >> 6;
    const int b  = blockIdx.x >> 8;            // 2048 blocks = 8 b x 256
    const int i0 = (blockIdx.x & 255) << 3;
    const float* Rb = R + b*LSEQ*3;

    for (int u = tid; u < LSEQ*3/4; u += 256)
        *(float4*)&Rl[u*4] = *(const float4*)&Rb[u*4];
    #pragma unroll
    for (int u = 0; u < TROWS; u++) hist[tid + 256*u] = 0u;
    if (tid < TROWS) { outPos[tid] = 0; candCnt[tid] = 0; fillCnt[tid] = 0; }
    __syncthreads();

    float xi[TROWS], yi[TROWS], zi[TROWS];
    #pragma unroll
    for (int c = 0; c < TROWS; c++) {
        xi[c] = Rl[(i0+c)*3+0]; yi[c] = Rl[(i0+c)*3+1]; zi[c] = Rl[(i0+c)*3+2];
    }

    // pass 1: histogram (in-cutoff, non-bonded only)
    #pragma unroll
    for (int u = 0; u < 8; u++) {
        int j = tid + (u << 8);
        float px = Rl[3*j], py = Rl[3*j+1], pz = Rl[3*j+2];
        #pragma unroll
        for (int c = 0; c < TROWS; c++) {
            float dx = xi[c]-px, dy = yi[c]-py, dz = zi[c]-pz;
            float d2 = dx*dx + dy*dy + dz*dz;
            int dd = j - (i0+c); dd = dd < 0 ? -dd : dd;
            if (dd > 3 && d2 < 144.0f)
                atomicAdd(&hist[c*256 + (int)(d2*BSCALE)], 1u);   // key in [0,254]
        }
    }
    __syncthreads();

    // scan: wave wv handles rows wv and wv+4; lane covers bins 4*lane..+3
    for (int rr = wv; rr < TROWS; rr += 4) {
        unsigned h4[4]; unsigned s = 0;
        #pragma unroll
        for (int v = 0; v < 4; v++) { h4[v] = hist[rr*256 + lane*4 + v]; s += h4[v]; }
        unsigned inc = s;
        #pragma unroll
        for (int off = 1; off < 64; off <<= 1) {
            unsigned n = __shfl_up(inc, off, 64);
            if (lane >= off) inc += n;
        }
        unsigned tot = __shfl(inc, 63, 64);
        unsigned excl = inc - s;
        if (tot < 64u) {
            if (lane == 0) { s_B[rr] = 255; s_need[rr] = 64 - (int)tot; }
        } else if (excl < 64u && 64u <= inc) {
            unsigned cc = excl;
            #pragma unroll
            for (int v = 0; v < 4; v++) {
                if (cc < 64u && 64u <= cc + h4[v]) { s_B[rr] = lane*4+v; s_need[rr] = 64 - (int)cc; }
                cc += h4[v];
            }
        }
    }
    __syncthreads();

    // pass 2: compact winners / boundary candidates / far-fill
    #pragma unroll
    for (int u = 0; u < 8; u++) {
        int j = tid + (u << 8);
        float px = Rl[3*j], py = Rl[3*j+1], pz = Rl[3*j+2];
        #pragma unroll
        for (int c = 0; c < TROWS; c++) {
            float dx = xi[c]-px, dy = yi[c]-py, dz = zi[c]-pz;
            float d2 = dx*dx + dy*dy + dz*dz;
            int dd = j - (i0+c); dd = dd < 0 ? -dd : dd;
            if (dd <= 3) continue;
            int B = s_B[c];
            int obase = (b*LSEQ + i0 + c)*KNB;
            if (d2 < 144.0f) {
                int key = (int)(d2*BSCALE);
                if (key < B) {
                    int pos = atomicAdd(&outPos[c], 1);
                    nbr[obase + pos] = j;
                } else if (key == B) {
                    int cc = atomicAdd(&candCnt[c], 1);
                    if (cc < 128) { cand_d2[c][cc] = d2; cand_j[c][cc] = j; }
                }
            } else if (B == 255) {
                // <64 inside cutoff: fill with r>=12 pairs (contribute exactly 0)
                int t = atomicAdd(&fillCnt[c], 1);
                if (t < s_need[c]) {
                    int pos = atomicAdd(&outPos[c], 1);
                    nbr[obase + pos] = j;
                }
            }
        }
    }
    __syncthreads();

    // boundary bin: exact rank
    for (int rr = wv; rr < TROWS; rr += 4) {
        int B = s_B[rr];
        if (B == 255) continue;
        int c = candCnt[rr]; if (c > 128) c = 128;
        int need = s_need[rr];
        int obase = (b*LSEQ + i0 + rr)*KNB;
        for (int ci = lane; ci < c; ci += 64) {
            float dv = cand_d2[rr][ci]; int jv = cand_j[rr][ci];
            int rank = 0;
            for (int x = 0; x < c; x++) {
                float dx2 = cand_d2[rr][x]; int jx = cand_j[rr][x];
                rank += (dx2 < dv) || (dx2 == dv && jx < jv);
            }
            if (rank < need) {
                int pos = atomicAdd(&outPos[rr], 1);
                nbr[obase + pos] = jv;
            }
        }
    }
}

// ---------------------------------------------------------------------------
// Kernel 2: pair MLP via bf16 MFMA, r3 structure + fixes.
//  - weights sharded: wave wv owns neuron tiles {2wv, 2wv+1} (64 VGPR frags)
//  - swapped operands (r4-verified): A=W (m=l15,k=q*8+j), B=act (n=l15 pair),
//    D (r=q*4+d neuron, c=l15 pair) -> packed b64 H-writes
//  - bias as MFMA C-operand (exact fp32)
//  - B-fragment reads include the +q*8 k-offset (r3 bug fixed)
//  - next tile's X inputs prefetched+packed into regs during GEMM phases
// ---------------------------------------------------------------------------
__device__ __forceinline__ void preload(
    int tile, int pl, int half,
    const int* __restrict__ nbr, const int* __restrict__ seq,
    const float* __restrict__ emb, const float* __restrict__ R,
    unsigned xp[12], float pR[6])
{
    int p  = tile*128 + pl;
    int bi = p >> 6;
    int bb = p >> 17;
    int jn = nbr[p];
    int rowj = (bb << 11) + jn;
    int si = seq[bi], sj = seq[rowj];
    const float4* ei = (const float4*)(emb + si*16 + half*8);
    const float4* ej = (const float4*)(emb + sj*16 + half*8);
    float4 a0 = ei[0], a1 = ei[1];
    float4 c0 = ej[0], c1 = ej[1];
    xp[0] = pkbf(a0.x, a0.y);  xp[1] = pkbf(a0.z, a0.w);
    xp[2] = pkbf(a1.x, a1.y);  xp[3] = pkbf(a1.z, a1.w);
    xp[4] = pkbf(c0.x, c0.y);  xp[5] = pkbf(c0.z, c0.w);
    xp[6] = pkbf(c1.x, c1.y);  xp[7] = pkbf(c1.z, c1.w);
    xp[8] = pkbf(a0.x*c0.x, a0.y*c0.y);  xp[9]  = pkbf(a0.z*c0.z, a0.w*c0.w);
    xp[10]= pkbf(a1.x*c1.x, a1.y*c1.y);  xp[11] = pkbf(a1.z*c1.z, a1.w*c1.w);
    if (!half) {
        pR[0] = R[bi*3+0];   pR[1] = R[bi*3+1];   pR[2] = R[bi*3+2];
        pR[3] = R[rowj*3+0]; pR[4] = R[rowj*3+1]; pR[5] = R[rowj*3+2];
    }
}

__global__ __launch_bounds__(256, 3) void mlp_mfma_kernel(
    const float* __restrict__ R, const int* __restrict__ seq,
    const float* __restrict__ emb,
    const float* __restrict__ W1, const float* __restrict__ b1,
    const float* __restrict__ W2, const float* __restrict__ b2,
    const float* __restrict__ W3, const float* __restrict__ b3,
    const float* __restrict__ centers, const float* __restrict__ widths,
    const int* __restrict__ nbr, float* __restrict__ out)
{
    __shared__ __align__(16) unsigned short Xs[128*XST];   // 18432 B
    __shared__ __align__(16) unsigned short Hs[128*HST];   // 34816 B
    __shared__ float r_s[128];
    __shared__ float bacc[BATCH];

    const int tid  = threadIdx.x;
    const int lane = tid & 63;
    const int wv   = tid >> 6;
    const int l15  = lane & 15;
    const int q    = lane >> 4;

    // ---- persistent A-operand weight fragments (wave-sharded neurons) ----
    short8 w1f[2][2], w2f[2][4], w3f[4];
    float b1v[2][4], b2v[2][4];
    #pragma unroll
    for (int mtl = 0; mtl < 2; mtl++) {
        int m = (2*wv + mtl)*16 + l15;
        #pragma unroll
        for (int d = 0; d < 4; d++) {
            b1v[mtl][d] = b1[(2*wv + mtl)*16 + q*4 + d];
            b2v[mtl][d] = b2[(2*wv + mtl)*16 + q*4 + d];
        }
        #pragma unroll
        for (int kt = 0; kt < 2; kt++)
            #pragma unroll
            for (int jj = 0; jj < 8; jj++) {
                int k = kt*32 + q*8 + jj;
                w1f[mtl][kt][jj] = (short)((k < 48) ? f2bf(W1[k*128 + m]) : 0);
            }
        #pragma unroll
        for (int kt = 0; kt < 4; kt++)
            #pragma unroll
            for (int jj = 0; jj < 8; jj++) {
                int k = kt*32 + q*8 + jj;
                w2f[mtl][kt][jj] = (short)f2bf(W2[k*128 + m]);
            }
    }
    #pragma unroll
    for (int kt = 0; kt < 4; kt++)
        #pragma unroll
        for (int jj = 0; jj < 8; jj++) {
            int k = kt*32 + q*8 + jj;
            w3f[kt][jj] = (short)((l15 < MRBF) ? f2bf(W3[k*MRBF + l15]) : 0);
        }
    float b3C[4], cen[4], i2w[4];
    #pragma unroll
    for (int d = 0; d < 4; d++) {
        int rb = q*4 + d;
        bool ok = rb < MRBF;
        b3C[d] = ok ? b3[rb] : 0.f;
        cen[d] = ok ? centers[rb] : 0.f;
        float wd = ok ? widths[rb] : 1.f;
        i2w[d] = 0.5f / (wd*wd);
    }
    if (tid < BATCH) bacc[tid] = 0.f;

    const int pl = tid >> 1, half = tid & 1;
    // zero-pad region (features 48..63) written once; constant across tiles
    *(uint4*)&Xs[pl*XST + 48 + half*8] = make_uint4(0u,0u,0u,0u);

    unsigned xp[12]; float pR[6];
    preload(blockIdx.x, pl, half, nbr, seq, emb, R, xp, pR);

    for (int tile = blockIdx.x; tile < NTILES; tile += gridDim.x) {
        __syncthreads();   // prior tile's readers done; init visible (1st iter)

        // ---- write X from prefetched packed regs ----
        {
            int base = pl*XST + half*8;
            *(uint4*)&Xs[base     ] = make_uint4(xp[0], xp[1], xp[2], xp[3]);
            *(uint4*)&Xs[base + 16] = make_uint4(xp[4], xp[5], xp[6], xp[7]);
            *(uint4*)&Xs[base + 32] = make_uint4(xp[8], xp[9], xp[10], xp[11]);
            if (!half) {
                float dx = pR[0]-pR[3], dy = pR[1]-pR[4], dz = pR[2]-pR[5];
                r_s[pl] = sqrtf(dx*dx + dy*dy + dz*dz + 1e-12f);
            }
        }
        __syncthreads();

        // ---- prefetch next tile (overlaps GEMM phases) ----
        int tn = tile + gridDim.x;
        if (tn < NTILES) preload(tn, pl, half, nbr, seq, emb, R, xp, pR);

        // ---- GEMM1: H1 = relu(W1^T X^T + b1), packed b64 writes ----
        #pragma unroll
        for (int nt = 0; nt < 8; nt++) {
            int arow = (nt*16 + l15)*XST + q*8;
            short8 x0 = *(const short8*)&Xs[arow];
            short8 x1 = *(const short8*)&Xs[arow + 32];
            #pragma unroll
            for (int mtl = 0; mtl < 2; mtl++) {
                floatx4 acc = {b1v[mtl][0], b1v[mtl][1], b1v[mtl][2], b1v[mtl][3]};
                acc = __builtin_amdgcn_mfma_f32_16x16x32_bf16(w1f[mtl][0], x0, acc, 0, 0, 0);
                acc = __builtin_amdgcn_mfma_f32_16x16x32_bf16(w1f[mtl][1], x1, acc, 0, 0, 0);
                *(uint2*)&Hs[(nt*16 + l15)*HST + (2*wv + mtl)*16 + q*4] =
                    make_uint2(pkbf(fmaxf(acc[0],0.f), fmaxf(acc[1],0.f)),
                               pkbf(fmaxf(acc[2],0.f), fmaxf(acc[3],0.f)));
            }
        }
        __syncthreads();

        // ---- GEMM2: read H1 (with +q*8 k-offset), hold packed H2 in regs ----
        uint2 h2p[8][2];
        #pragma unroll
        for (int nt = 0; nt < 8; nt++) {
            int arow = (nt*16 + l15)*HST + q*8;
            short8 hf[4];
            #pragma unroll
            for (int kt = 0; kt < 4; kt++)
                hf[kt] = *(const short8*)&Hs[arow + kt*32];
            #pragma unroll
            for (int mtl = 0; mtl < 2; mtl++) {
                floatx4 acc = {b2v[mtl][0], b2v[mtl][1], b2v[mtl][2], b2v[mtl][3]};
                acc = __builtin_amdgcn_mfma_f32_16x16x32_bf16(w2f[mtl][0], hf[0], acc, 0, 0, 0);
                acc = __builtin_amdgcn_mfma_f32_16x16x32_bf16(w2f[mtl][1], hf[1], acc, 0, 0, 0);
                acc = __builtin_amdgcn_mfma_f32_16x16x32_bf16(w2f[mtl][2], hf[2], acc, 0, 0, 0);
                acc = __builtin_amdgcn_mfma_f32_16x16x32_bf16(w2f[mtl][3], hf[3], acc, 0, 0, 0);
                h2p[nt][mtl] = make_uint2(pkbf(fmaxf(acc[0],0.f), fmaxf(acc[1],0.f)),
                                          pkbf(fmaxf(acc[2],0.f), fmaxf(acc[3],0.f)));
            }
        }
        __syncthreads();   // all H1 reads complete
        #pragma unroll
        for (int nt = 0; nt < 8; nt++)
            #pragma unroll
            for (int mtl = 0; mtl < 2; mtl++)
                *(uint2*)&Hs[(nt*16 + l15)*HST + (2*wv + mtl)*16 + q*4] = h2p[nt][mtl];
        __syncthreads();

        // ---- GEMM3 (W3^T H2^T) + epilogue; wave owns pair-tiles 2wv,2wv+1 ----
        float esum = 0.f;
        #pragma unroll
        for (int ntl = 0; ntl < 2; ntl++) {
            int nt = 2*wv + ntl;
            int arow = (nt*16 + l15)*HST + q*8;
            floatx4 acc = {b3C[0], b3C[1], b3C[2], b3C[3]};
            #pragma unroll
            for (int kt = 0; kt < 4; kt++) {
                short8 hf = *(const short8*)&Hs[arow + kt*32];
                acc = __builtin_amdgcn_mfma_f32_16x16x32_bf16(w3f[kt], hf, acc, 0, 0, 0);
            }
            float rr = r_s[nt*16 + l15];
            if (rr < 12.0f) {   // uniform within each xor16/32 shuffle group
                float att = 0.f;
                #pragma unroll
                for (int d = 0; d < 4; d++) {
                    if (q*4 + d < MRBF) {
                        float x = acc[d];
                        float sp = fmaxf(x, 0.f) + __logf(1.f + __expf(-fabsf(x)));
                        float df = rr - cen[d];
                        att += sp * __expf(-df*df*i2w[d]);
                    }
                }
                att += __shfl_xor(att, 16, 64);
                att += __shfl_xor(att, 32, 64);
                float t = fminf(fmaxf((rr - 10.f)*0.5f, 0.f), 1.f);
                float sw = 1.f - t*t*(3.f - 2.f*t);
                esum -= att * sw;   // 4x quad-replicated; x0.25 at flush
            }
        }
        #pragma unroll
        for (int off = 1; off < 64; off <<= 1)
            esum += __shfl_xor(esum, off, 64);
        if (lane == 0) atomicAdd(&bacc[tile >> 10], esum * 0.25f);
    }
    __syncthreads();
    if (tid < BATCH) atomicAdd(&out[tid], bacc[tid]);
}

// ---------------------------------------------------------------------------
extern "C" void kernel_launch(void* const* d_in, const int* in_sizes, int n_in,
                              void* d_out, int out_size, void* d_ws, size_t ws_size,
                              hipStream_t stream) {
    const float* R       = (const float*)d_in[0];
    const int*   seq     = (const int*)  d_in[1];
    const float* emb     = (const float*)d_in[2];
    const float* W1      = (const float*)d_in[3];
    const float* b1      = (const float*)d_in[4];
    const float* W2      = (const float*)d_in[5];
    const float* b2      = (const float*)d_in[6];
    const float* W3      = (const float*)d_in[7];
    const float* b3      = (const float*)d_in[8];
    const float* centers = (const float*)d_in[9];
    const float* widths  = (const float*)d_in[10];
    float* out = (float*)d_out;
    int*   nbr = (int*)d_ws;   // NPAIRS ints = 4 MiB

    hipMemsetAsync(d_out, 0, out_size * sizeof(float), stream);

    topk_kernel<<<BATCH*(LSEQ/TROWS), 256, 0, stream>>>(R, nbr);
    mlp_mfma_kernel<<<2048, 256, 0, stream>>>(R, seq, emb, W1, b1, W2, b2, W3, b3,
                                              centers, widths, nbr, out);
}